// Round 1
// baseline (337.939 us; speedup 1.0000x reference)
//
#include <hip/hip_runtime.h>

// Fused actor-critic forward for S=256,B=1024,D=64,H=128,A=8.
// N = S*B = 262144 independent rows (LSTM is zero-state per step).
// One block = 128 rows, 4 waves x 32 rows. All GEMMs: mfma_f32_16x16x32_bf16,
// arg0 = weight frag (out-feature dim), arg1 = activation frag (batch dim):
// acc comes out feature-contiguous per lane -> packed b64 LDS writebacks.

#define NROWS (256 * 1024)
#define DIN  64
#define HID  128
#define ACTD 8

typedef __attribute__((ext_vector_type(8))) short s16x8;
typedef __attribute__((ext_vector_type(4))) float fx4;
typedef __attribute__((ext_vector_type(2))) unsigned int u32x2;
typedef __attribute__((ext_vector_type(4))) unsigned int u32x4;

__device__ __forceinline__ unsigned int f2bf_u(float f) {
  unsigned int u = __float_as_uint(f);
  u += 0x7FFFu + ((u >> 16) & 1u);   // RNE
  return u >> 16;
}

__device__ __forceinline__ float fsig(float x) {
  return __builtin_amdgcn_rcpf(1.0f + __expf(-x));      // safe at +-inf
}
__device__ __forceinline__ float ftanh(float x) {
  return 2.0f * __builtin_amdgcn_rcpf(1.0f + __expf(-2.0f * x)) - 1.0f;
}

// Stage an [R][C] fp32 row-major global tile into LDS as bf16, 16B chunks,
// XOR swizzle (chunk ^= row&7) matching all fragment reads. C = 8<<c8shift.
__device__ __forceinline__ void stage_tile(const float* __restrict__ g,
                                           unsigned short* lds, int nchunks,
                                           int c8shift, int tid) {
  char* lb = (char*)lds;
  for (int idx = tid; idx < nchunks; idx += 256) {
    int r = idx >> c8shift;
    int c = idx & ((1 << c8shift) - 1);
    const fx4* gp = (const fx4*)(g + (size_t)idx * 8);
    fx4 v0 = gp[0];
    fx4 v1 = gp[1];
    u32x4 u;
    u[0] = f2bf_u(v0[0]) | (f2bf_u(v0[1]) << 16);
    u[1] = f2bf_u(v0[2]) | (f2bf_u(v0[3]) << 16);
    u[2] = f2bf_u(v1[0]) | (f2bf_u(v1[1]) << 16);
    u[3] = f2bf_u(v1[2]) | (f2bf_u(v1[3]) << 16);
    int byte = (r << (c8shift + 4)) + ((c << 4) ^ ((r & 7) << 4));
    *(u32x4*)(lb + byte) = u;
  }
}

// 8 bf16 from swizzled tile: row -> lane&15, 8 contiguous along K.
__device__ __forceinline__ s16x8 frag_ld(const unsigned short* base, int row,
                                         int kbyte, int rowsh) {
  int byte = (row << rowsh) + (kbyte ^ ((row & 7) << 4));
  return *(const s16x8*)((const char*)base + byte);
}

template <int NIT>
__device__ __forceinline__ void zacc(fx4 acc[2][NIT]) {
#pragma unroll
  for (int j = 0; j < 2; ++j)
#pragma unroll
    for (int i = 0; i < NIT; ++i) acc[j][i] = fx4{0.f, 0.f, 0.f, 0.f};
}

// D[i=feat][j=batch]: arg0 = weight frag rows it*16+(l&15), arg1 = act frag
// rows jrow+(l&15). Output: lane holds 4 consecutive feats of batch (l&15).
template <int NIT, int NKC, int ASH, int WSH>
__device__ __forceinline__ void gemm_t(const unsigned short* wt,
                                       const unsigned short* at, int jrow,
                                       int lane, fx4 acc[2][NIT]) {
  const int l15 = lane & 15;
  const int kb0 = (lane >> 4) << 4;
#pragma unroll
  for (int kc = 0; kc < NKC; ++kc) {
    int kbyte = kc * 64 + kb0;
    s16x8 a0 = frag_ld(at, jrow + l15, kbyte, ASH);
    s16x8 a1 = frag_ld(at, jrow + 16 + l15, kbyte, ASH);
#pragma unroll
    for (int it = 0; it < NIT; ++it) {
      s16x8 wf = frag_ld(wt, it * 16 + l15, kbyte, WSH);
      acc[0][it] = __builtin_amdgcn_mfma_f32_16x16x32_bf16(wf, a0, acc[0][it], 0, 0, 0);
      acc[1][it] = __builtin_amdgcn_mfma_f32_16x16x32_bf16(wf, a1, acc[1][it], 0, 0, 0);
    }
  }
}

__device__ __forceinline__ void add_bias2(fx4 acc[2][8],
                                          const float* __restrict__ b0,
                                          const float* __restrict__ b1,
                                          int lane) {
  const int g4 = (lane >> 4) << 2;
#pragma unroll
  for (int it = 0; it < 8; ++it) {
    int n0 = it * 16 + g4;
    fx4 bv = *(const fx4*)(b0 + n0) + *(const fx4*)(b1 + n0);
    acc[0][it] += bv;
    acc[1][it] += bv;
  }
}

// relu(acc+bias) -> bf16 -> swizzled LDS act tile ([row][feat], 256B rows)
__device__ __forceinline__ void epi_relu(fx4 acc[2][8],
                                         const float* __restrict__ bias,
                                         unsigned short* obuf, int jrow,
                                         int lane) {
  const int g4 = (lane >> 4) << 2;
  const int l15 = lane & 15;
  char* ob = (char*)obuf;
#pragma unroll
  for (int it = 0; it < 8; ++it) {
    int n0 = it * 16 + g4;
    fx4 bv = *(const fx4*)(bias + n0);
#pragma unroll
    for (int jt = 0; jt < 2; ++jt) {
      fx4 v = acc[jt][it] + bv;
#pragma unroll
      for (int r = 0; r < 4; ++r) v[r] = fmaxf(v[r], 0.0f);
      u32x2 u;
      u[0] = f2bf_u(v[0]) | (f2bf_u(v[1]) << 16);
      u[1] = f2bf_u(v[2]) | (f2bf_u(v[3]) << 16);
      int m = jrow + jt * 16 + l15;
      int byte = (m << 8) + ((n0 * 2) ^ ((m & 7) << 4));
      *(u32x2*)(ob + byte) = u;
    }
  }
}

__global__ __launch_bounds__(256, 2) void fused_ac(
    const float* __restrict__ state,
    const float* __restrict__ aw1, const float* __restrict__ ab1,
    const float* __restrict__ aw2, const float* __restrict__ ab2,
    const float* __restrict__ cw1, const float* __restrict__ cb1,
    const float* __restrict__ cw2, const float* __restrict__ cb2,
    const float* __restrict__ awih, const float* __restrict__ abih,
    const float* __restrict__ abhh, const float* __restrict__ cwih,
    const float* __restrict__ cbih, const float* __restrict__ cbhh,
    const float* __restrict__ mw, const float* __restrict__ mb,
    const float* __restrict__ lw, const float* __restrict__ lb,
    const float* __restrict__ vw, const float* __restrict__ vb,
    float* __restrict__ outp) {
  __shared__ __align__(16) unsigned short abuf[HID * HID];   // 32KB act ping
  __shared__ __align__(16) unsigned short wbuf[HID * HID];   // 32KB weights (+X for GEMM1)
  __shared__ __align__(16) unsigned short hwbuf[16 * HID];   // 4KB [mw;lw]

  const int tid = threadIdx.x;
  const int lane = tid & 63;
  const int jrow = (tid >> 6) << 5;   // 32 rows per wave
  const int rbase = blockIdx.x << 7;  // 128 rows per block
  const int l15 = lane & 15;
  const int g4 = (lane >> 4) << 2;

  stage_tile(mw, hwbuf, 8 * 16, 4, tid);            // head rows 0-7
  stage_tile(lw, hwbuf + 8 * HID, 8 * 16, 4, tid);  // head rows 8-15

  float* meanp = outp;
  float* stdp = outp + (size_t)NROWS * ACTD;
  float* valp = outp + (size_t)NROWS * ACTD * 2;

  for (int p = 0; p < 2; ++p) {  // p=0 actor, p=1 critic
    const float* w1 = p ? cw1 : aw1;
    const float* b1 = p ? cb1 : ab1;
    const float* w2 = p ? cw2 : aw2;
    const float* b2 = p ? cb2 : ab2;
    const float* wih = p ? cwih : awih;
    const float* bih = p ? cbih : abih;
    const float* bhh = p ? cbhh : abhh;

    __syncthreads();  // prior readers of wbuf/abuf done
    stage_tile(w1, wbuf, HID * 8, 3, tid);                                  // W1 [128][64]
    stage_tile(state + (size_t)rbase * DIN, wbuf + HID * DIN, HID * 8, 3, tid);  // X [128][64]
    __syncthreads();

    fx4 acc[2][8];
    zacc<8>(acc);
    gemm_t<8, 2, 7, 7>(wbuf, wbuf + HID * DIN, jrow, lane, acc);  // H1 = X*W1^T
    __syncthreads();
    epi_relu(acc, b1, abuf, jrow, lane);
    stage_tile(w2, wbuf, HID * 16, 4, tid);
    __syncthreads();

    zacc<8>(acc);
    gemm_t<8, 4, 8, 8>(wbuf, abuf, jrow, lane, acc);  // H2 = H1*W2^T
    __syncthreads();
    epi_relu(acc, b2, abuf, jrow, lane);

    // LSTM gates (zero state): need i (rows 0-127), g (256-383), o (384-511)
    stage_tile(wih, wbuf, HID * 16, 4, tid);
    __syncthreads();
    fx4 gi[2][8];
    zacc<8>(gi);
    gemm_t<8, 4, 8, 8>(wbuf, abuf, jrow, lane, gi);
    __syncthreads();
    add_bias2(gi, bih, bhh, lane);

    stage_tile(wih + 256 * HID, wbuf, HID * 16, 4, tid);
    __syncthreads();
    fx4 gg[2][8];
    zacc<8>(gg);
    gemm_t<8, 4, 8, 8>(wbuf, abuf, jrow, lane, gg);
    __syncthreads();
    add_bias2(gg, bih + 256, bhh + 256, lane);

    // gi := tanh(c) = tanh(sig(i)*tanh(g))
#pragma unroll
    for (int jt = 0; jt < 2; ++jt)
#pragma unroll
      for (int it = 0; it < 8; ++it)
#pragma unroll
        for (int r = 0; r < 4; ++r) {
          float cc = fsig(gi[jt][it][r]) * ftanh(gg[jt][it][r]);
          gi[jt][it][r] = ftanh(cc);
        }

    stage_tile(wih + 384 * HID, wbuf, HID * 16, 4, tid);
    __syncthreads();
    fx4 go[2][8];
    zacc<8>(go);
    gemm_t<8, 4, 8, 8>(wbuf, abuf, jrow, lane, go);
    __syncthreads();  // abuf reads done; safe to overwrite with h
    add_bias2(go, bih + 384, bhh + 384, lane);

    if (p == 0) {
      // actor h -> abuf, then mean/std head GEMM (hwbuf rows 0-15)
      char* ob = (char*)abuf;
#pragma unroll
      for (int it = 0; it < 8; ++it)
#pragma unroll
        for (int jt = 0; jt < 2; ++jt) {
          float h0 = fsig(go[jt][it][0]) * gi[jt][it][0];
          float h1 = fsig(go[jt][it][1]) * gi[jt][it][1];
          float h2 = fsig(go[jt][it][2]) * gi[jt][it][2];
          float h3 = fsig(go[jt][it][3]) * gi[jt][it][3];
          u32x2 u;
          u[0] = f2bf_u(h0) | (f2bf_u(h1) << 16);
          u[1] = f2bf_u(h2) | (f2bf_u(h3) << 16);
          int m = jrow + jt * 16 + l15;
          int n0 = it * 16 + g4;
          int byte = (m << 8) + ((n0 * 2) ^ ((m & 7) << 4));
          *(u32x2*)(ob + byte) = u;
        }
      __syncthreads();
      fx4 ha[2][1];
      zacc<1>(ha);
      gemm_t<1, 4, 8, 8>(hwbuf, abuf, jrow, lane, ha);
      bool isMean = (g4 < 8);
      fx4 hb = isMean ? *(const fx4*)(mb + g4) : *(const fx4*)(lb + (g4 - 8));
#pragma unroll
      for (int jt = 0; jt < 2; ++jt) {
        fx4 v = ha[jt][0] + hb;
        int m = rbase + jrow + jt * 16 + l15;
        if (isMean) {
          *(fx4*)(meanp + (size_t)m * ACTD + g4) = v;
        } else {
#pragma unroll
          for (int r = 0; r < 4; ++r) v[r] = __expf(v[r]);
          *(fx4*)(stdp + (size_t)m * ACTD + (g4 - 8)) = v;
        }
      }
    } else {
      // critic: value = vw . h, h never leaves registers
      float vs0 = 0.f, vs1 = 0.f;
#pragma unroll
      for (int it = 0; it < 8; ++it) {
        fx4 w4 = *(const fx4*)(vw + it * 16 + g4);
#pragma unroll
        for (int r = 0; r < 4; ++r) {
          vs0 += w4[r] * (fsig(go[0][it][r]) * gi[0][it][r]);
          vs1 += w4[r] * (fsig(go[1][it][r]) * gi[1][it][r]);
        }
      }
      vs0 += __shfl_xor(vs0, 16);
      vs0 += __shfl_xor(vs0, 32);
      vs1 += __shfl_xor(vs1, 16);
      vs1 += __shfl_xor(vs1, 32);
      if (lane < 16) {
        valp[rbase + jrow + lane] = vs0 + vb[0];
        valp[rbase + jrow + 16 + lane] = vs1 + vb[0];
      }
    }
  }
}

extern "C" void kernel_launch(void* const* d_in, const int* in_sizes, int n_in,
                              void* d_out, int out_size, void* d_ws,
                              size_t ws_size, hipStream_t stream) {
  (void)in_sizes; (void)n_in; (void)d_ws; (void)ws_size; (void)out_size;
  const float* state = (const float*)d_in[0];
  const float* aw1 = (const float*)d_in[1];
  const float* ab1 = (const float*)d_in[2];
  const float* aw2 = (const float*)d_in[3];
  const float* ab2 = (const float*)d_in[4];
  const float* cw1 = (const float*)d_in[5];
  const float* cb1 = (const float*)d_in[6];
  const float* cw2 = (const float*)d_in[7];
  const float* cb2 = (const float*)d_in[8];
  const float* awih = (const float*)d_in[9];
  // d_in[10] = a_whh (unused: zero-state LSTM)
  const float* abih = (const float*)d_in[11];
  const float* abhh = (const float*)d_in[12];
  const float* cwih = (const float*)d_in[13];
  // d_in[14] = c_whh (unused)
  const float* cbih = (const float*)d_in[15];
  const float* cbhh = (const float*)d_in[16];
  const float* mw = (const float*)d_in[17];
  const float* mb = (const float*)d_in[18];
  const float* lw = (const float*)d_in[19];
  const float* lb = (const float*)d_in[20];
  const float* vw = (const float*)d_in[21];
  const float* vb = (const float*)d_in[22];

  fused_ac<<<NROWS / 128, 256, 0, stream>>>(
      state, aw1, ab1, aw2, ab2, cw1, cb1, cw2, cb2, awih, abih, abhh, cwih,
      cbih, cbhh, mw, mb, lw, lb, vw, vb, (float*)d_out);
}

// Round 2
// 153.964 us; speedup vs baseline: 2.1949x; 2.1949x over previous
//
#include <hip/hip_runtime.h>

// Fused actor-critic forward for S=256,B=1024,D=64,H=128,A=8.
// N = S*B = 262144 independent rows (LSTM is zero-state per step).
// R1: weights pre-converted to bf16 + pre-swizzled LDS images in d_ws (prep
// kernel), staged via global_load_lds width-16 DMA; actor/critic split into
// separate blocks (grid 4096, path-major) to halve the per-block serial chain.

#define NROWS (256 * 1024)
#define DIN  64
#define HID  128
#define ACTD 8

// ws layout (bytes)
#define W1_OFF   0        // [128][64]  bf16 image, 16384 B
#define W2_OFF   16384    // [128][128] 32768 B
#define WI_OFF   49152    // wih rows 0..127
#define WG_OFF   81920    // wih rows 256..383
#define WO_OFF   114688   // wih rows 384..511
#define PSTR     147456   // per-path stride (actor at 0, critic at PSTR)
#define HEAD_OFF 294912   // [mw(8x128) ; lw(8x128)] images, 4096 B
#define GB_OFF   299008   // combined gate bias bih+bhh, 512 f32 per path
#define WS_TOTAL 303104

typedef __attribute__((ext_vector_type(8))) short s16x8;
typedef __attribute__((ext_vector_type(4))) float fx4;
typedef __attribute__((ext_vector_type(2))) unsigned int u32x2;
typedef __attribute__((ext_vector_type(4))) unsigned int u32x4;

__device__ __forceinline__ unsigned int f2bf_u(float f) {
  unsigned int u = __float_as_uint(f);
  u += 0x7FFFu + ((u >> 16) & 1u);   // RNE
  return u >> 16;
}

__device__ __forceinline__ float fsig(float x) {
  return __builtin_amdgcn_rcpf(1.0f + __expf(-x));
}
__device__ __forceinline__ float ftanh(float x) {
  return 2.0f * __builtin_amdgcn_rcpf(1.0f + __expf(-2.0f * x)) - 1.0f;
}

// async 16B global->LDS DMA (linear dest; source is pre-swizzled image)
__device__ __forceinline__ void dma16(const void* g, void* l) {
  __builtin_amdgcn_global_load_lds(
      (__attribute__((address_space(1))) void*)(g),
      (__attribute__((address_space(3))) void*)(l), 16, 0, 0);
}

// Stage an [R][C] fp32 row-major global tile into LDS as bf16, 16B chunks,
// XOR swizzle (chunk ^= row&7). C = 8<<c8shift. (Used for the X tile only.)
__device__ __forceinline__ void stage_tile(const float* __restrict__ g,
                                           unsigned short* lds, int nchunks,
                                           int c8shift, int tid) {
  char* lb = (char*)lds;
  for (int idx = tid; idx < nchunks; idx += 256) {
    int r = idx >> c8shift;
    int c = idx & ((1 << c8shift) - 1);
    const fx4* gp = (const fx4*)(g + (size_t)idx * 8);
    fx4 v0 = gp[0];
    fx4 v1 = gp[1];
    u32x4 u;
    u[0] = f2bf_u(v0[0]) | (f2bf_u(v0[1]) << 16);
    u[1] = f2bf_u(v0[2]) | (f2bf_u(v0[3]) << 16);
    u[2] = f2bf_u(v1[0]) | (f2bf_u(v1[1]) << 16);
    u[3] = f2bf_u(v1[2]) | (f2bf_u(v1[3]) << 16);
    int byte = (r << (c8shift + 4)) + ((c << 4) ^ ((r & 7) << 4));
    *(u32x4*)(lb + byte) = u;
  }
}

// 8 bf16 from swizzled tile: row -> lane&15, 8 contiguous along K.
__device__ __forceinline__ s16x8 frag_ld(const unsigned short* base, int row,
                                         int kbyte, int rowsh) {
  int byte = (row << rowsh) + (kbyte ^ ((row & 7) << 4));
  return *(const s16x8*)((const char*)base + byte);
}

template <int NIT>
__device__ __forceinline__ void zacc(fx4 acc[2][NIT]) {
#pragma unroll
  for (int j = 0; j < 2; ++j)
#pragma unroll
    for (int i = 0; i < NIT; ++i) acc[j][i] = fx4{0.f, 0.f, 0.f, 0.f};
}

// D[i=feat][j=batch]: arg0 = weight frag rows it*16+(l&15), arg1 = act frag
// rows jrow+(l&15). Output: lane holds 4 consecutive feats of batch (l&15).
template <int NIT, int NKC, int ASH, int WSH>
__device__ __forceinline__ void gemm_t(const unsigned short* wt,
                                       const unsigned short* at, int jrow,
                                       int lane, fx4 acc[2][NIT]) {
  const int l15 = lane & 15;
  const int kb0 = (lane >> 4) << 4;
#pragma unroll
  for (int kc = 0; kc < NKC; ++kc) {
    int kbyte = kc * 64 + kb0;
    s16x8 a0 = frag_ld(at, jrow + l15, kbyte, ASH);
    s16x8 a1 = frag_ld(at, jrow + 16 + l15, kbyte, ASH);
#pragma unroll
    for (int it = 0; it < NIT; ++it) {
      s16x8 wf = frag_ld(wt, it * 16 + l15, kbyte, WSH);
      acc[0][it] = __builtin_amdgcn_mfma_f32_16x16x32_bf16(wf, a0, acc[0][it], 0, 0, 0);
      acc[1][it] = __builtin_amdgcn_mfma_f32_16x16x32_bf16(wf, a1, acc[1][it], 0, 0, 0);
    }
  }
}

__device__ __forceinline__ void add_bias(fx4 acc[2][8],
                                         const float* __restrict__ b, int lane) {
  const int g4 = (lane >> 4) << 2;
#pragma unroll
  for (int it = 0; it < 8; ++it) {
    fx4 bv = *(const fx4*)(b + it * 16 + g4);
    acc[0][it] += bv;
    acc[1][it] += bv;
  }
}

// relu(acc+bias) -> bf16 -> swizzled LDS act tile ([row][feat], 256B rows)
__device__ __forceinline__ void epi_relu(fx4 acc[2][8],
                                         const float* __restrict__ bias,
                                         unsigned short* obuf, int jrow,
                                         int lane) {
  const int g4 = (lane >> 4) << 2;
  const int l15 = lane & 15;
  char* ob = (char*)obuf;
#pragma unroll
  for (int it = 0; it < 8; ++it) {
    int n0 = it * 16 + g4;
    fx4 bv = *(const fx4*)(bias + n0);
#pragma unroll
    for (int jt = 0; jt < 2; ++jt) {
      fx4 v = acc[jt][it] + bv;
#pragma unroll
      for (int r = 0; r < 4; ++r) v[r] = fmaxf(v[r], 0.0f);
      u32x2 u;
      u[0] = f2bf_u(v[0]) | (f2bf_u(v[1]) << 16);
      u[1] = f2bf_u(v[2]) | (f2bf_u(v[3]) << 16);
      int m = jrow + jt * 16 + l15;
      int byte = (m << 8) + ((n0 * 2) ^ ((m & 7) << 4));
      *(u32x2*)(ob + byte) = u;
    }
  }
}

// ---------------- prep: fp32 weights -> bf16 pre-swizzled images in ws -----
__global__ void prep_weights(const float* __restrict__ aw1,
                             const float* __restrict__ aw2,
                             const float* __restrict__ awih,
                             const float* __restrict__ cw1,
                             const float* __restrict__ cw2,
                             const float* __restrict__ cwih,
                             const float* __restrict__ mw,
                             const float* __restrict__ lw,
                             const float* __restrict__ abih,
                             const float* __restrict__ abhh,
                             const float* __restrict__ cbih,
                             const float* __restrict__ cbhh,
                             char* __restrict__ ws) {
  int y = blockIdx.y;
  int idx = blockIdx.x * 256 + threadIdx.x;
  if (y >= 12) {  // combined gate biases
    if (idx < 512) {
      float* dst = (float*)(ws + GB_OFF + (size_t)(y - 12) * 2048);
      const float* b0 = (y == 12) ? abih : cbih;
      const float* b1 = (y == 12) ? abhh : cbhh;
      dst[idx] = b0[idx] + b1[idx];
    }
    return;
  }
  const float* src;
  int nch, sh, off;
  switch (y) {
    case 0:  src = aw1;              nch = 1024; sh = 3; off = W1_OFF;        break;
    case 1:  src = aw2;              nch = 2048; sh = 4; off = W2_OFF;        break;
    case 2:  src = awih;             nch = 2048; sh = 4; off = WI_OFF;        break;
    case 3:  src = awih + 256 * HID; nch = 2048; sh = 4; off = WG_OFF;        break;
    case 4:  src = awih + 384 * HID; nch = 2048; sh = 4; off = WO_OFF;        break;
    case 5:  src = cw1;              nch = 1024; sh = 3; off = PSTR + W1_OFF; break;
    case 6:  src = cw2;              nch = 2048; sh = 4; off = PSTR + W2_OFF; break;
    case 7:  src = cwih;             nch = 2048; sh = 4; off = PSTR + WI_OFF; break;
    case 8:  src = cwih + 256 * HID; nch = 2048; sh = 4; off = PSTR + WG_OFF; break;
    case 9:  src = cwih + 384 * HID; nch = 2048; sh = 4; off = PSTR + WO_OFF; break;
    case 10: src = mw;               nch = 128;  sh = 4; off = HEAD_OFF;      break;
    default: src = lw;               nch = 128;  sh = 4; off = HEAD_OFF + 2048; break;
  }
  if (idx >= nch) return;
  int r = idx >> sh;
  int c = idx & ((1 << sh) - 1);
  const fx4* gp = (const fx4*)(src + (size_t)idx * 8);
  fx4 v0 = gp[0];
  fx4 v1 = gp[1];
  u32x4 u;
  u[0] = f2bf_u(v0[0]) | (f2bf_u(v0[1]) << 16);
  u[1] = f2bf_u(v0[2]) | (f2bf_u(v0[3]) << 16);
  u[2] = f2bf_u(v1[0]) | (f2bf_u(v1[1]) << 16);
  u[3] = f2bf_u(v1[2]) | (f2bf_u(v1[3]) << 16);
  int byte = (r << (sh + 4)) + ((c << 4) ^ ((r & 7) << 4));
  *(u32x4*)(ws + off + byte) = u;
}

// ---------------- main fused kernel: one path x 128 rows per block ---------
__global__ __launch_bounds__(256, 2) void fused_ac(
    const float* __restrict__ state,
    const float* __restrict__ ab1, const float* __restrict__ ab2,
    const float* __restrict__ cb1, const float* __restrict__ cb2,
    const float* __restrict__ mb, const float* __restrict__ lb,
    const float* __restrict__ vw, const float* __restrict__ vb,
    const char* __restrict__ ws, float* __restrict__ outp) {
  __shared__ __align__(16) unsigned short abuf[HID * HID];   // 32KB act
  __shared__ __align__(16) unsigned short wbuf[HID * HID];   // 32KB weights (+X in GEMM1)
  __shared__ __align__(16) unsigned short hwbuf[16 * HID];   // 4KB [mw;lw]

  const int tid = threadIdx.x;
  const int lane = tid & 63;
  const int jrow = (tid >> 6) << 5;          // 32 rows per wave
  const int path = blockIdx.x >> 11;         // 0 actor, 1 critic (path-major)
  const int rbase = (blockIdx.x & 2047) << 7;
  const int l15 = lane & 15;
  const int g4 = (lane >> 4) << 2;

  const char* wsp = ws + (size_t)path * PSTR;
  const float* b1 = path ? cb1 : ab1;
  const float* b2 = path ? cb2 : ab2;
  const float* gbias = (const float*)(ws + GB_OFF + (size_t)path * 2048);
  char* wb = (char*)wbuf;

  float* meanp = outp;
  float* stdp = outp + (size_t)NROWS * ACTD;
  float* valp = outp + (size_t)NROWS * ACTD * 2;

  // S0: DMA W1 image (+ head images for actor); reg-stage X with fp32->bf16
  for (int i = tid; i < 1024; i += 256) dma16(wsp + W1_OFF + i * 16, wb + i * 16);
  if (path == 0)
    for (int i = tid; i < 256; i += 256)
      dma16(ws + HEAD_OFF + i * 16, (char*)hwbuf + i * 16);
  stage_tile(state + (size_t)rbase * DIN, wbuf + 8192, HID * 8, 3, tid);
  __syncthreads();

  fx4 acc[2][8];
  zacc<8>(acc);
  gemm_t<8, 2, 7, 7>(wbuf, wbuf + 8192, jrow, lane, acc);  // H1 = X*W1^T
  __syncthreads();
  for (int i = tid; i < 2048; i += 256) dma16(wsp + W2_OFF + i * 16, wb + i * 16);
  epi_relu(acc, b1, abuf, jrow, lane);
  __syncthreads();

  zacc<8>(acc);
  gemm_t<8, 4, 8, 8>(wbuf, abuf, jrow, lane, acc);         // H2 = H1*W2^T
  __syncthreads();
  for (int i = tid; i < 2048; i += 256) dma16(wsp + WI_OFF + i * 16, wb + i * 16);
  epi_relu(acc, b2, abuf, jrow, lane);
  __syncthreads();

  fx4 gi[2][8];
  zacc<8>(gi);
  gemm_t<8, 4, 8, 8>(wbuf, abuf, jrow, lane, gi);          // i gate
  __syncthreads();
  for (int i = tid; i < 2048; i += 256) dma16(wsp + WG_OFF + i * 16, wb + i * 16);
  add_bias(gi, gbias, lane);
  __syncthreads();

  fx4 gg[2][8];
  zacc<8>(gg);
  gemm_t<8, 4, 8, 8>(wbuf, abuf, jrow, lane, gg);          // g gate
  __syncthreads();
  for (int i = tid; i < 2048; i += 256) dma16(wsp + WO_OFF + i * 16, wb + i * 16);
  add_bias(gg, gbias + 256, lane);
  // gi := tanh(c) = tanh(sig(i)*tanh(g))   (hides the WO DMA latency)
#pragma unroll
  for (int jt = 0; jt < 2; ++jt)
#pragma unroll
    for (int it = 0; it < 8; ++it)
#pragma unroll
      for (int r = 0; r < 4; ++r) {
        float cc = fsig(gi[jt][it][r]) * ftanh(gg[jt][it][r]);
        gi[jt][it][r] = ftanh(cc);
      }
  __syncthreads();

  fx4 go[2][8];
  zacc<8>(go);
  gemm_t<8, 4, 8, 8>(wbuf, abuf, jrow, lane, go);          // o gate
  add_bias(go, gbias + 384, lane);

  if (path == 0) {
    // actor: h -> abuf, then mean/std head GEMM
    __syncthreads();  // all waves done reading abuf(H2)
    char* ob = (char*)abuf;
#pragma unroll
    for (int it = 0; it < 8; ++it)
#pragma unroll
      for (int jt = 0; jt < 2; ++jt) {
        float h0 = fsig(go[jt][it][0]) * gi[jt][it][0];
        float h1 = fsig(go[jt][it][1]) * gi[jt][it][1];
        float h2 = fsig(go[jt][it][2]) * gi[jt][it][2];
        float h3 = fsig(go[jt][it][3]) * gi[jt][it][3];
        u32x2 u;
        u[0] = f2bf_u(h0) | (f2bf_u(h1) << 16);
        u[1] = f2bf_u(h2) | (f2bf_u(h3) << 16);
        int m = jrow + jt * 16 + l15;
        int n0 = it * 16 + g4;
        int byte = (m << 8) + ((n0 * 2) ^ ((m & 7) << 4));
        *(u32x2*)(ob + byte) = u;
      }
    __syncthreads();
    fx4 ha[2][1];
    zacc<1>(ha);
    gemm_t<1, 4, 8, 8>(hwbuf, abuf, jrow, lane, ha);
    bool isMean = (g4 < 8);
    fx4 hb = isMean ? *(const fx4*)(mb + g4) : *(const fx4*)(lb + (g4 - 8));
#pragma unroll
    for (int jt = 0; jt < 2; ++jt) {
      fx4 v = ha[jt][0] + hb;
      int m = rbase + jrow + jt * 16 + l15;
      if (isMean) {
        *(fx4*)(meanp + (size_t)m * ACTD + g4) = v;
      } else {
#pragma unroll
        for (int r = 0; r < 4; ++r) v[r] = __expf(v[r]);
        *(fx4*)(stdp + (size_t)m * ACTD + (g4 - 8)) = v;
      }
    }
  } else {
    // critic: value = vw . h, h never leaves registers
    float vs0 = 0.f, vs1 = 0.f;
#pragma unroll
    for (int it = 0; it < 8; ++it) {
      fx4 w4 = *(const fx4*)(vw + it * 16 + g4);
#pragma unroll
      for (int r = 0; r < 4; ++r) {
        vs0 += w4[r] * (fsig(go[0][it][r]) * gi[0][it][r]);
        vs1 += w4[r] * (fsig(go[1][it][r]) * gi[1][it][r]);
      }
    }
    vs0 += __shfl_xor(vs0, 16);
    vs0 += __shfl_xor(vs0, 32);
    vs1 += __shfl_xor(vs1, 16);
    vs1 += __shfl_xor(vs1, 32);
    if (lane < 16) {
      valp[rbase + jrow + lane] = vs0 + vb[0];
      valp[rbase + jrow + 16 + lane] = vs1 + vb[0];
    }
  }
}

extern "C" void kernel_launch(void* const* d_in, const int* in_sizes, int n_in,
                              void* d_out, int out_size, void* d_ws,
                              size_t ws_size, hipStream_t stream) {
  (void)in_sizes; (void)n_in; (void)ws_size; (void)out_size;
  const float* state = (const float*)d_in[0];
  const float* aw1 = (const float*)d_in[1];
  const float* ab1 = (const float*)d_in[2];
  const float* aw2 = (const float*)d_in[3];
  const float* ab2 = (const float*)d_in[4];
  const float* cw1 = (const float*)d_in[5];
  const float* cb1 = (const float*)d_in[6];
  const float* cw2 = (const float*)d_in[7];
  const float* cb2 = (const float*)d_in[8];
  const float* awih = (const float*)d_in[9];
  // d_in[10] = a_whh (unused: zero-state LSTM)
  const float* abih = (const float*)d_in[11];
  const float* abhh = (const float*)d_in[12];
  const float* cwih = (const float*)d_in[13];
  // d_in[14] = c_whh (unused)
  const float* cbih = (const float*)d_in[15];
  const float* cbhh = (const float*)d_in[16];
  const float* mw = (const float*)d_in[17];
  const float* mb = (const float*)d_in[18];
  const float* lw = (const float*)d_in[19];
  const float* lb = (const float*)d_in[20];
  const float* vw = (const float*)d_in[21];
  const float* vb = (const float*)d_in[22];
  char* ws = (char*)d_ws;

  prep_weights<<<dim3(8, 14), 256, 0, stream>>>(
      aw1, aw2, awih, cw1, cw2, cwih, mw, lw, abih, abhh, cbih, cbhh, ws);
  fused_ac<<<4096, 256, 0, stream>>>(
      state, ab1, ab2, cb1, cb2, mb, lb, vw, vb, ws, (float*)d_out);
}